// Round 1
// 232.857 us; speedup vs baseline: 1.7816x; 1.7816x over previous
//
#include <hip/hip_runtime.h>
#include <hip/hip_bf16.h>

typedef __bf16 bf16x8_t __attribute__((ext_vector_type(8)));
typedef float  f32x4_t  __attribute__((ext_vector_type(4)));
typedef short  short8_t __attribute__((ext_vector_type(8)));
typedef short  short4_t __attribute__((ext_vector_type(4)));

#define NB   4
#define NH   16
#define SEQ  2048
#define HD   64
#define BQ   64
#define BKV  64
#define LSTR 72   // LDS row stride in bf16 elems: 144B rows, 16B-aligned blocks

// masked score in base-2 domain: WHERE_CONST * log2(e)
#define MASK2 (-14426.950408889634f)
// softmax scale folded into Q: (1/sqrt(64)) * log2(e)
#define QSCL  (0.18033688011112042f)

// uniform swizzled LDS address (shorts): row*72 + ((blk ^ (row>>3)) & 7) * 8
__device__ __forceinline__ int swz(int rowi, int blk) {
    return rowi * LSTR + (((blk) ^ (rowi >> 3)) & 7) * 8;
}

__global__ void __launch_bounds__(256)
fa_fwd(const float* __restrict__ qg,
       const float* __restrict__ kg,
       const float* __restrict__ vg,
       float* __restrict__ outg) {
    __shared__ alignas(16) short k_lds[BKV * LSTR];   // K tile bf16 [kv][d], block-swizzled
    __shared__ alignas(16) short vt_lds[HD * LSTR];   // V^T tile bf16 [d][kv], block-swizzled
    __shared__ alignas(16) short p_lds[BQ * LSTR];    // P bf16 [q][kv], block-swizzled

    const int tid  = threadIdx.x;
    const int wave = tid >> 6;
    const int lane = tid & 63;
    const int l16  = lane & 15;
    const int quad = lane >> 4;

    // grid: x = bh (64), y = q-tile; y reversed so ALL heaviest blocks dispatch first
    const int bh = blockIdx.x;
    const int qt = (int)gridDim.y - 1 - (int)blockIdx.y;
    const int q0 = qt * BQ;

    const size_t base = (size_t)bh * SEQ * HD;
    const float* qp = qg + base;
    const float* kp = kg + base;
    const float* vp = vg + base;

    // ---- Q A-fragments (bf16, scale pre-folded): A[m=l16][k=quad*8+j] / [32+...] ----
    bf16x8_t qf0, qf1;
    {
        const float* qr = qp + (size_t)(q0 + wave * 16 + l16) * HD;
        f32x4_t qa = *(const f32x4_t*)(qr + quad * 8);
        f32x4_t qb = *(const f32x4_t*)(qr + quad * 8 + 4);
        f32x4_t qc = *(const f32x4_t*)(qr + 32 + quad * 8);
        f32x4_t qd = *(const f32x4_t*)(qr + 32 + quad * 8 + 4);
        #pragma unroll
        for (int j = 0; j < 4; ++j) {
            qf0[j]     = (__bf16)(qa[j] * QSCL);
            qf0[4 + j] = (__bf16)(qb[j] * QSCL);
            qf1[j]     = (__bf16)(qc[j] * QSCL);
            qf1[4 + j] = (__bf16)(qd[j] * QSCL);
        }
    }

    f32x4_t o_acc[4];
    const f32x4_t zero4 = {0.0f, 0.0f, 0.0f, 0.0f};
    #pragma unroll
    for (int c = 0; c < 4; ++c) o_acc[c] = zero4;
    float m_r[4], l_r[4];
    #pragma unroll
    for (int r = 0; r < 4; ++r) { m_r[r] = MASK2; l_r[r] = 0.0f; }

    // ---- staging addressing (constant per thread) ----
    const int srow = tid >> 4;     // base row within tile for it=0 (0..15), +16 per it
    const int cb   = tid & 15;     // float4-block in d
    const int d0   = cb * 4;

    // staging registers: tile data in flight during compute
    f32x4_t kreg[4], vreg[4];

    auto issue = [&](int kt0) {
        const float* kr = kp + (size_t)kt0 * HD + d0;
        const float* vr = vp + (size_t)kt0 * HD + d0;
        #pragma unroll
        for (int it = 0; it < 4; ++it) {
            const size_t off = (size_t)(it * 16 + srow) * HD;
            kreg[it] = *(const f32x4_t*)(kr + off);
            vreg[it] = *(const f32x4_t*)(vr + off);
        }
    };

    auto stage = [&]() {
        #pragma unroll
        for (int it = 0; it < 4; ++it) {
            const int r0 = it * 16 + srow;
            // K: 4 consecutive d stay inside one 8-block -> one 8B write
            short4_t kw;
            #pragma unroll
            for (int j = 0; j < 4; ++j) kw[j] = __builtin_bit_cast(short, (__bf16)kreg[it][j]);
            *(short4_t*)&k_lds[swz(r0, cb >> 1) + (d0 & 7)] = kw;
            // V^T: 4 scalar b16 writes (transpose)
            #pragma unroll
            for (int j = 0; j < 4; ++j)
                vt_lds[swz(d0 + j, r0 >> 3) + (r0 & 7)] = __builtin_bit_cast(short, (__bf16)vreg[it][j]);
        }
    };

    issue(0);   // prologue: tile 0 in flight

    const int ntiles = qt + 1;
    for (int t = 0; t < ntiles; ++t) {
        const int kt0 = t * BKV;
        __syncthreads();            // A: prior iteration's LDS readers done
        stage();                    // regs (tile t) -> LDS, bf16 convert
        __syncthreads();            // B: staged tile visible
        if (t + 1 < ntiles) issue(kt0 + BKV);   // tile t+1 in flight during compute

        // ---- S = Q K^T  (D[m=q][n=kv]; scale already folded into Q) ----
        f32x4_t s_acc[4];
        #pragma unroll
        for (int c = 0; c < 4; ++c) s_acc[c] = zero4;
        #pragma unroll
        for (int c = 0; c < 4; ++c) {
            const int kvrow = c * 16 + l16;
            bf16x8_t b0 = __builtin_bit_cast(bf16x8_t, *(const short8_t*)&k_lds[swz(kvrow, quad)]);
            bf16x8_t b1 = __builtin_bit_cast(bf16x8_t, *(const short8_t*)&k_lds[swz(kvrow, quad + 4)]);
            s_acc[c] = __builtin_amdgcn_mfma_f32_16x16x32_bf16(qf0, b0, s_acc[c], 0, 0, 0);
            s_acc[c] = __builtin_amdgcn_mfma_f32_16x16x32_bf16(qf1, b1, s_acc[c], 0, 0, 0);
        }

        // ---- online softmax (C layout: row = quad*4+r, col = c*16+l16) ----
        float sv[4][4];
        float vmax[4] = {MASK2, MASK2, MASK2, MASK2};
        const bool diag = (kt0 == q0);
        #pragma unroll
        for (int c = 0; c < 4; ++c) {
            #pragma unroll
            for (int r = 0; r < 4; ++r) {
                float x = s_acc[c][r];
                if (diag) {
                    int col = c * 16 + l16;
                    int row = wave * 16 + quad * 4 + r;
                    if (col > row) x = MASK2;
                }
                sv[c][r] = x;
                vmax[r] = fmaxf(vmax[r], x);
            }
        }
        #pragma unroll
        for (int r = 0; r < 4; ++r) {
            vmax[r] = fmaxf(vmax[r], __shfl_xor(vmax[r], 1));
            vmax[r] = fmaxf(vmax[r], __shfl_xor(vmax[r], 2));
            vmax[r] = fmaxf(vmax[r], __shfl_xor(vmax[r], 4));
            vmax[r] = fmaxf(vmax[r], __shfl_xor(vmax[r], 8));
        }

        // rescale only when some row's max actually grew (first tiles mostly)
        bool grow = (vmax[0] > m_r[0]) | (vmax[1] > m_r[1]) |
                    (vmax[2] > m_r[2]) | (vmax[3] > m_r[3]);
        if (__any((int)grow)) {
            #pragma unroll
            for (int r = 0; r < 4; ++r) {
                float mn = fmaxf(m_r[r], vmax[r]);
                float a  = __builtin_amdgcn_exp2f(m_r[r] - mn);   // arg <= 0 by construction
                m_r[r] = mn;
                l_r[r] *= a;
                #pragma unroll
                for (int c = 0; c < 4; ++c) o_acc[c][r] *= a;
            }
        }

        // ---- P = exp2(sv - m); row sums; write P to LDS (C layout, swizzled) ----
        float rs[4] = {0.0f, 0.0f, 0.0f, 0.0f};
        #pragma unroll
        for (int c = 0; c < 4; ++c) {
            #pragma unroll
            for (int r = 0; r < 4; ++r) {
                float p = __builtin_amdgcn_exp2f(sv[c][r] - m_r[r]);  // arg <= 0
                rs[r] += p;
                int prow = wave * 16 + quad * 4 + r;
                p_lds[swz(prow, 2 * c + (l16 >> 3)) + (l16 & 7)] =
                    __builtin_bit_cast(short, (__bf16)p);
            }
        }
        #pragma unroll
        for (int r = 0; r < 4; ++r) {
            rs[r] += __shfl_xor(rs[r], 1);
            rs[r] += __shfl_xor(rs[r], 2);
            rs[r] += __shfl_xor(rs[r], 4);
            rs[r] += __shfl_xor(rs[r], 8);
            l_r[r] += rs[r];
        }

        // NO barrier: P rows are written and read by the same wave (lgkmcnt orders)

        // ---- O += P V  (A = P[m=q][k=kv], B = V^T rows as B[k=kv][n=d]) ----
        const int prow = wave * 16 + l16;
        bf16x8_t pf0 = __builtin_bit_cast(bf16x8_t, *(const short8_t*)&p_lds[swz(prow, quad)]);
        bf16x8_t pf1 = __builtin_bit_cast(bf16x8_t, *(const short8_t*)&p_lds[swz(prow, quad + 4)]);
        #pragma unroll
        for (int c = 0; c < 4; ++c) {
            const int d = c * 16 + l16;
            bf16x8_t b0 = __builtin_bit_cast(bf16x8_t, *(const short8_t*)&vt_lds[swz(d, quad)]);
            bf16x8_t b1 = __builtin_bit_cast(bf16x8_t, *(const short8_t*)&vt_lds[swz(d, quad + 4)]);
            o_acc[c] = __builtin_amdgcn_mfma_f32_16x16x32_bf16(pf0, b0, o_acc[c], 0, 0, 0);
            o_acc[c] = __builtin_amdgcn_mfma_f32_16x16x32_bf16(pf1, b1, o_acc[c], 0, 0, 0);
        }
    }

    // ---- epilogue: O / l, fp32 store to out[b][q][h*64 + d] ----
    const int b = bh >> 4;
    const int h = bh & 15;
    #pragma unroll
    for (int r = 0; r < 4; ++r) {
        const int row = q0 + wave * 16 + quad * 4 + r;
        const float inv_l = 1.0f / fmaxf(l_r[r], 1e-30f);
        float* op = outg + ((size_t)b * SEQ + row) * (NH * HD) + h * HD;
        #pragma unroll
        for (int c = 0; c < 4; ++c) {
            float val = o_acc[c][r] * inv_l;
            unsigned bits = __builtin_bit_cast(unsigned, val);
            if ((bits & 0x7F800000u) == 0x7F800000u) val = 0.0f;  // scrub inf/NaN
            op[c * 16 + l16] = val;
        }
    }
}

extern "C" void kernel_launch(void* const* d_in, const int* in_sizes, int n_in,
                              void* d_out, int out_size, void* d_ws, size_t ws_size,
                              hipStream_t stream) {
    const float* q = (const float*)d_in[0];
    const float* k = (const float*)d_in[1];
    const float* v = (const float*)d_in[2];
    float* out = (float*)d_out;
    dim3 grid(NB * NH, SEQ / BQ);   // x = bh, y = q-tile (reversed in-kernel: heavy first)
    fa_fwd<<<grid, 256, 0, stream>>>(q, k, v, out);
}

// Round 2
// 191.797 us; speedup vs baseline: 2.1630x; 1.2141x over previous
//
#include <hip/hip_runtime.h>
#include <hip/hip_bf16.h>

typedef __bf16 bf16x8_t __attribute__((ext_vector_type(8)));
typedef float  f32x4_t  __attribute__((ext_vector_type(4)));
typedef short  short8_t __attribute__((ext_vector_type(8)));
typedef short  short4_t __attribute__((ext_vector_type(4)));

#define NB   4
#define NH   16
#define SEQ  2048
#define HD   64
#define BQ   64
#define BKV  64
#define LSTR 72   // LDS row stride in bf16 elems: 144B rows, 16B-aligned blocks

// masked score in base-2 domain: WHERE_CONST * log2(e)
#define MASK2 (-14426.950408889634f)
// softmax scale folded into Q: (1/sqrt(64)) * log2(e)
#define QSCL  (0.18033688011112042f)

// uniform swizzled LDS address (shorts): row*72 + ((blk ^ (row>>3)) & 7) * 8
__device__ __forceinline__ int swz(int rowi, int blk) {
    return rowi * LSTR + (((blk) ^ (rowi >> 3)) & 7) * 8;
}

__global__ void __launch_bounds__(256)
fa_fwd(const float* __restrict__ qg,
       const float* __restrict__ kg,
       const float* __restrict__ vg,
       float* __restrict__ outg) {
    __shared__ alignas(16) short k_lds[BKV * LSTR];   // K tile bf16 [kv][d], block-swizzled
    __shared__ alignas(16) short vt_lds[HD * LSTR];   // V^T tile bf16 [d][kv], block-swizzled
    __shared__ alignas(16) short p_lds[BQ * LSTR];    // P bf16 [q][kv], block-swizzled

    const int tid  = threadIdx.x;
    const int wave = tid >> 6;
    const int lane = tid & 63;
    const int l16  = lane & 15;
    const int quad = lane >> 4;

    // grid: x = bh (64), y = q-tile; y reversed so ALL heaviest blocks dispatch first
    const int bh = blockIdx.x;
    const int qt = (int)gridDim.y - 1 - (int)blockIdx.y;
    const int q0 = qt * BQ;

    const size_t base = (size_t)bh * SEQ * HD;
    const float* qp = qg + base;
    const float* kp = kg + base;
    const float* vp = vg + base;

    // ---- Q fragments (B-operand in swapped QK^T; layout same as A): q=l16, d=quad*8+j ----
    bf16x8_t qf0, qf1;
    {
        const float* qr = qp + (size_t)(q0 + wave * 16 + l16) * HD;
        f32x4_t qa = *(const f32x4_t*)(qr + quad * 8);
        f32x4_t qb = *(const f32x4_t*)(qr + quad * 8 + 4);
        f32x4_t qc = *(const f32x4_t*)(qr + 32 + quad * 8);
        f32x4_t qd = *(const f32x4_t*)(qr + 32 + quad * 8 + 4);
        #pragma unroll
        for (int j = 0; j < 4; ++j) {
            qf0[j]     = (__bf16)(qa[j] * QSCL);
            qf0[4 + j] = (__bf16)(qb[j] * QSCL);
            qf1[j]     = (__bf16)(qc[j] * QSCL);
            qf1[4 + j] = (__bf16)(qd[j] * QSCL);
        }
    }

    f32x4_t o_acc[4];
    const f32x4_t zero4 = {0.0f, 0.0f, 0.0f, 0.0f};
    #pragma unroll
    for (int c = 0; c < 4; ++c) o_acc[c] = zero4;
    // scalar online-softmax state: this lane's q row is wave*16 + l16
    float m_x = MASK2, l_x = 0.0f;

    // ---- staging addressing: thread owns rows 4*sr..4*sr+3, d block d0..d0+3 ----
    const int sr = tid >> 4;      // 0..15
    const int cb = tid & 15;
    const int d0 = cb * 4;

    f32x4_t kreg[4], vreg[4];     // tile data in flight during compute

    auto issue = [&](int kt0) {
        const float* kr = kp + (size_t)(kt0 + 4 * sr) * HD + d0;
        const float* vr = vp + (size_t)(kt0 + 4 * sr) * HD + d0;
        #pragma unroll
        for (int i = 0; i < 4; ++i) {
            kreg[i] = *(const f32x4_t*)(kr + i * HD);
            vreg[i] = *(const f32x4_t*)(vr + i * HD);
        }
    };

    auto stage = [&]() {
        // K rows: 4 consecutive d in one 8-block -> one 8B write per row
        #pragma unroll
        for (int i = 0; i < 4; ++i) {
            const int r0 = 4 * sr + i;
            short4_t kw;
            #pragma unroll
            for (int j = 0; j < 4; ++j) kw[j] = __builtin_bit_cast(short, (__bf16)kreg[i][j]);
            *(short4_t*)&k_lds[swz(r0, cb >> 1) + (cb & 1) * 4] = kw;
        }
        // V^T: register-transpose the 4x4 block -> 4 contiguous kv per d -> 8B writes
        #pragma unroll
        for (int j = 0; j < 4; ++j) {
            short4_t vw;
            #pragma unroll
            for (int i = 0; i < 4; ++i) vw[i] = __builtin_bit_cast(short, (__bf16)vreg[i][j]);
            *(short4_t*)&vt_lds[swz(d0 + j, sr >> 1) + (sr & 1) * 4] = vw;
        }
    };

    issue(0);   // prologue: tile 0 in flight

    const int ntiles = qt + 1;
    for (int t = 0; t < ntiles; ++t) {
        const int kt0 = t * BKV;
        __syncthreads();            // A: prior iteration's LDS readers done
        stage();                    // regs (tile t) -> LDS, bf16 convert
        __syncthreads();            // B: staged tile visible
        if (t + 1 < ntiles) issue(kt0 + BKV);   // tile t+1 in flight during compute

        // ---- S^T = K Q^T : D[m=kv][n=q];  kv = c*16+quad*4+r, q = l16 ----
        f32x4_t s_acc[4];
        #pragma unroll
        for (int c = 0; c < 4; ++c) s_acc[c] = zero4;
        __builtin_amdgcn_s_setprio(1);
        #pragma unroll
        for (int c = 0; c < 4; ++c) {
            const int kvrow = c * 16 + l16;
            bf16x8_t kf0 = __builtin_bit_cast(bf16x8_t, *(const short8_t*)&k_lds[swz(kvrow, quad)]);
            bf16x8_t kf1 = __builtin_bit_cast(bf16x8_t, *(const short8_t*)&k_lds[swz(kvrow, quad + 4)]);
            s_acc[c] = __builtin_amdgcn_mfma_f32_16x16x32_bf16(kf0, qf0, s_acc[c], 0, 0, 0);
            s_acc[c] = __builtin_amdgcn_mfma_f32_16x16x32_bf16(kf1, qf1, s_acc[c], 0, 0, 0);
        }
        __builtin_amdgcn_s_setprio(0);

        // ---- online softmax: all 16 values belong to this lane's q row ----
        float sv[4][4];
        float vmax = MASK2;
        const bool diag = (kt0 == q0);
        const int qloc = wave * 16 + l16;   // unused unless diag; kv local = c*16+quad*4+r
        #pragma unroll
        for (int c = 0; c < 4; ++c) {
            #pragma unroll
            for (int r = 0; r < 4; ++r) {
                float x = s_acc[c][r];
                if (diag && (c * 16 + quad * 4 + r > qloc)) x = MASK2;
                sv[c][r] = x;
                vmax = fmaxf(vmax, x);
            }
        }
        // combine across the 4 quads holding the other kv subsets of this q row
        vmax = fmaxf(vmax, __shfl_xor(vmax, 16));
        vmax = fmaxf(vmax, __shfl_xor(vmax, 32));

        // rescale only when some row's max actually grew
        if (__any((int)(vmax > m_x))) {
            float mn = fmaxf(m_x, vmax);
            float a  = __builtin_amdgcn_exp2f(m_x - mn);   // arg <= 0
            m_x = mn;
            l_x *= a;
            float ar[4];
            #pragma unroll
            for (int r = 0; r < 4; ++r)
                ar[r] = __shfl(a, (lane & 48) | (quad * 4 + r));   // alpha of o_acc's row
            #pragma unroll
            for (int c = 0; c < 4; ++c)
                #pragma unroll
                for (int r = 0; r < 4; ++r)
                    o_acc[c][r] *= ar[r];
        }

        // ---- P = exp2(sv - m); row sum; write P (4 contiguous kv per c -> 8B writes) ----
        const int prow = wave * 16 + l16;
        float rs = 0.0f;
        #pragma unroll
        for (int c = 0; c < 4; ++c) {
            short4_t pw;
            #pragma unroll
            for (int r = 0; r < 4; ++r) {
                float p = __builtin_amdgcn_exp2f(sv[c][r] - m_x);  // arg <= 0
                rs += p;
                pw[r] = __builtin_bit_cast(short, (__bf16)p);
            }
            *(short4_t*)&p_lds[swz(prow, 2 * c + (quad >> 1)) + (quad & 1) * 4] = pw;
        }
        rs += __shfl_xor(rs, 16);
        rs += __shfl_xor(rs, 32);
        l_x += rs;

        // NO barrier: P tile is written and read within the same wave (lgkmcnt orders)

        // ---- O += P V  (A = P[m=q][k=kv], B = V^T rows as B[k=kv][n=d]) ----
        bf16x8_t pf0 = __builtin_bit_cast(bf16x8_t, *(const short8_t*)&p_lds[swz(prow, quad)]);
        bf16x8_t pf1 = __builtin_bit_cast(bf16x8_t, *(const short8_t*)&p_lds[swz(prow, quad + 4)]);
        __builtin_amdgcn_s_setprio(1);
        #pragma unroll
        for (int c = 0; c < 4; ++c) {
            const int d = c * 16 + l16;
            bf16x8_t b0 = __builtin_bit_cast(bf16x8_t, *(const short8_t*)&vt_lds[swz(d, quad)]);
            bf16x8_t b1 = __builtin_bit_cast(bf16x8_t, *(const short8_t*)&vt_lds[swz(d, quad + 4)]);
            o_acc[c] = __builtin_amdgcn_mfma_f32_16x16x32_bf16(pf0, b0, o_acc[c], 0, 0, 0);
            o_acc[c] = __builtin_amdgcn_mfma_f32_16x16x32_bf16(pf1, b1, o_acc[c], 0, 0, 0);
        }
        __builtin_amdgcn_s_setprio(0);
    }

    // ---- epilogue: O / l, fp32 store to out[b][q][h*64 + d] ----
    const int b = bh >> 4;
    const int h = bh & 15;
    #pragma unroll
    for (int r = 0; r < 4; ++r) {
        const float lr = __shfl(l_x, (lane & 48) | (quad * 4 + r));   // l of o_acc's row
        const float inv_l = 1.0f / fmaxf(lr, 1e-30f);
        const int row = q0 + wave * 16 + quad * 4 + r;
        float* op = outg + ((size_t)b * SEQ + row) * (NH * HD) + h * HD;
        #pragma unroll
        for (int c = 0; c < 4; ++c) {
            float val = o_acc[c][r] * inv_l;
            unsigned bits = __builtin_bit_cast(unsigned, val);
            if ((bits & 0x7F800000u) == 0x7F800000u) val = 0.0f;  // scrub inf/NaN
            op[c * 16 + l16] = val;
        }
    }
}

extern "C" void kernel_launch(void* const* d_in, const int* in_sizes, int n_in,
                              void* d_out, int out_size, void* d_ws, size_t ws_size,
                              hipStream_t stream) {
    const float* q = (const float*)d_in[0];
    const float* k = (const float*)d_in[1];
    const float* v = (const float*)d_in[2];
    float* out = (float*)d_out;
    dim3 grid(NB * NH, SEQ / BQ);   // x = bh, y = q-tile (reversed in-kernel: heavy first)
    fa_fwd<<<grid, 256, 0, stream>>>(q, k, v, out);
}